// Round 7
// baseline (638.619 us; speedup 1.0000x reference)
//
#include <hip/hip_runtime.h>

// ---------------------------------------------------------------------------
// Transformer block on MI355X. Inputs fp32, output fp32.
// GEMMs + attention via MFMA 16x16x32 bf16. Gate FUSED into rmsnorm2 (fp32
// logits). Routing lists atomics-free (ballot). MoE sparse top-2.
// R7: all GEMM K-loops -> BK=32, 3-buffer, 2-deep prefetch with COUNTED
// vmcnt (T4): r5/r6's vmcnt(0) drained the just-issued prefetch every
// K-step (r6 post-mortem: gemm_glu regressed 24us when BK halved the
// compute window per drain). Now the wait for tile k fires two iterations
// after its issue -> HBM latency fully covered; vmcnt never 0 in-loop.
// 2-tensor GEMMs: 48KB LDS (3 blk/CU); 3-tensor GLU: 72KB (2 blk/CU).
// Same K order -> bitwise-identical output. Workspace peak ~93 MB.
// ---------------------------------------------------------------------------

typedef __bf16 bf16_t;
typedef __bf16 bf16x8 __attribute__((ext_vector_type(8)));
typedef __bf16 bf16x4 __attribute__((ext_vector_type(4)));
typedef float  f32x4  __attribute__((ext_vector_type(4)));

#define LQKV 1536

#define GLD16(gp, lp) __builtin_amdgcn_global_load_lds(                         \
    (const __attribute__((address_space(1))) void*)(gp),                        \
    (__attribute__((address_space(3))) void*)(lp), 16, 0, 0)

// pre-compute barrier: wait for tile-k loads only (counted), then barrier.
// L2s/L1s are string literals of 2*L and L (L = loads/thread/STAGE).
#define WAIT_BAR(ahead, L2s, L1s) do {                                          \
    if ((ahead) == 2)      asm volatile("s_waitcnt vmcnt(" L2s ")" ::: "memory");\
    else if ((ahead) == 1) asm volatile("s_waitcnt vmcnt(" L1s ")" ::: "memory");\
    else                   asm volatile("s_waitcnt vmcnt(0)" ::: "memory");     \
    __builtin_amdgcn_s_barrier();                                               \
} while (0)

// post-compute barrier: LDS reads done (lgkm only -- vmcnt stays in flight)
#define BAR_LGKM() do {                                                         \
    asm volatile("s_waitcnt lgkmcnt(0)" ::: "memory");                          \
    __builtin_amdgcn_s_barrier();                                               \
} while (0)

// ---------------------------------------------------------------------------
// fp32 -> bf16 convert, 4 elems/thread (single tensor)
// ---------------------------------------------------------------------------
__global__ __launch_bounds__(256) void convert_k(
    const float* __restrict__ src, bf16_t* __restrict__ dst)
{
    size_t i = (size_t)blockIdx.x * 256 + threadIdx.x;
    float4 v = *((const float4*)src + i);
    bf16x4 o;
    o[0] = (bf16_t)v.x; o[1] = (bf16_t)v.y; o[2] = (bf16_t)v.z; o[3] = (bf16_t)v.w;
    *((bf16x4*)dst + i) = o;
}

// ---------------------------------------------------------------------------
// Multi-tensor fp32 -> bf16 convert: up to 8 segments in one launch.
// ---------------------------------------------------------------------------
struct Cvt8 {
    const float* s[8];
    bf16_t* d[8];
    int cum[9];
    int nseg;
};

__global__ __launch_bounds__(256) void convert_multi_k(Cvt8 j)
{
    int blk = blockIdx.x;
    int seg = 0;
    while (seg + 1 < j.nseg && blk >= j.cum[seg + 1]) ++seg;
    size_t i = (size_t)(blk - j.cum[seg]) * 256 + threadIdx.x;
    float4 v = *((const float4*)j.s[seg] + i);
    bf16x4 o;
    o[0] = (bf16_t)v.x; o[1] = (bf16_t)v.y; o[2] = (bf16_t)v.z; o[3] = (bf16_t)v.w;
    *((bf16x4*)j.d[seg] + i) = o;
}

// ---------------------------------------------------------------------------
// MFMA GEMM, BK=32, 3-buf 2-deep counted-vmcnt: C[m,n] = sum_k A[m,k]*W[n,k]
// mode 0: outF = acc; mode 1: outB = bf16(acc);
// mode 2: outF = acc + resF (and outF2 = same if non-null);
// mode 3: outF += acc (non-atomic RMW)
// ---------------------------------------------------------------------------
__global__ __launch_bounds__(256) void gemm_bt(
    const bf16_t* __restrict__ A, const bf16_t* __restrict__ W,
    int M, int N, int K, int ldw, int mode,
    float* __restrict__ outF, bf16_t* __restrict__ outB,
    const float* __restrict__ resF, float* __restrict__ outF2)
{
    __shared__ __align__(16) bf16_t sA[3][128 * 32];
    __shared__ __align__(16) bf16_t sB[3][128 * 32];
    const int tid  = threadIdx.x;
    const int bm   = blockIdx.y * 128, bn = blockIdx.x * 128;
    const int lane = tid & 63;
    const int wv   = tid >> 6;
    const int wm   = (wv >> 1) * 64, wn = (wv & 1) * 64;
    const int lr   = lane & 15;
    const int kg   = lane >> 4;
    const int rsw  = (lr >> 1) & 3;

    f32x4 acc[4][4];
    #pragma unroll
    for (int i = 0; i < 4; ++i)
        #pragma unroll
        for (int j = 0; j < 4; ++j)
            acc[i][j] = f32x4{0.f, 0.f, 0.f, 0.f};

    auto STAGE = [&](int b, int k0) {           // 4 loads/thread
        #pragma unroll
        for (int p = 0; p < 2; ++p) {
            int idx = p * 256 + tid;
            int row = idx >> 2;
            int ch  = 8 * ((idx & 3) ^ ((idx >> 3) & 3));
            GLD16(A + (size_t)(bm + row) * K   + k0 + ch, sA[b] + idx * 8);
            GLD16(W + (size_t)(bn + row) * ldw + k0 + ch, sB[b] + idx * 8);
        }
    };

    const int T = K >> 5;
    STAGE(0, 0);
    if (T > 1) STAGE(1, 32);
    int b0 = 0, b1 = 1, b2 = 2;
    for (int kt = 0; kt < T; ++kt) {
        if (kt + 2 < T) STAGE(b2, (kt + 2) * 32);
        int ahead = (kt + 2 < T) ? 2 : ((kt + 1 < T) ? 1 : 0);
        WAIT_BAR(ahead, "8", "4");
        const bf16_t* sAr = sA[b0];
        const bf16_t* sBr = sB[b0];
        bf16x8 af[4], bfr[4];
        #pragma unroll
        for (int i = 0; i < 4; ++i)
            af[i] = *(const bf16x8*)(sAr + (wm + i * 16 + lr) * 32 + 8 * (kg ^ rsw));
        #pragma unroll
        for (int j = 0; j < 4; ++j)
            bfr[j] = *(const bf16x8*)(sBr + (wn + j * 16 + lr) * 32 + 8 * (kg ^ rsw));
        #pragma unroll
        for (int i = 0; i < 4; ++i)
            #pragma unroll
            for (int j = 0; j < 4; ++j)
                acc[i][j] = __builtin_amdgcn_mfma_f32_16x16x32_bf16(
                    af[i], bfr[j], acc[i][j], 0, 0, 0);
        BAR_LGKM();
        int t = b0; b0 = b1; b1 = b2; b2 = t;
    }

    #pragma unroll
    for (int i = 0; i < 4; ++i) {
        #pragma unroll
        for (int j = 0; j < 4; ++j) {
            #pragma unroll
            for (int rr = 0; rr < 4; ++rr) {
                int m = bm + wm + i * 16 + kg * 4 + rr;
                int n = bn + wn + j * 16 + lr;
                size_t o = (size_t)m * N + n;
                float v = acc[i][j][rr];
                if (mode == 0)      outF[o] = v;
                else if (mode == 1) outB[o] = (bf16_t)v;
                else if (mode == 2) {
                    float r = v + resF[o];
                    outF[o] = r;
                    if (outF2) outF2[o] = r;
                } else              outF[o] += v;
            }
        }
    }
}

// ---------------------------------------------------------------------------
// Fused GLU GEMM (dense, shared expert), BK=32 3-buf 2-deep (72KB):
// out = bf16(silu(A@W1^T) * (A@W2^T))
// ---------------------------------------------------------------------------
__global__ __launch_bounds__(256) void gemm_glu(
    const bf16_t* __restrict__ A, const bf16_t* __restrict__ W1,
    const bf16_t* __restrict__ W2, int M, int N, int K,
    bf16_t* __restrict__ out)
{
    __shared__ __align__(16) bf16_t sA[3][128 * 32];
    __shared__ __align__(16) bf16_t sB1[3][128 * 32];
    __shared__ __align__(16) bf16_t sB2[3][128 * 32];
    const int tid  = threadIdx.x;
    const int bm   = blockIdx.y * 128, bn = blockIdx.x * 128;
    const int lane = tid & 63;
    const int wv   = tid >> 6;
    const int wm   = (wv >> 1) * 64, wn = (wv & 1) * 64;
    const int lr   = lane & 15;
    const int kg   = lane >> 4;
    const int rsw  = (lr >> 1) & 3;

    f32x4 acc1[4][4], acc2[4][4];
    #pragma unroll
    for (int i = 0; i < 4; ++i)
        #pragma unroll
        for (int j = 0; j < 4; ++j) {
            acc1[i][j] = f32x4{0.f, 0.f, 0.f, 0.f};
            acc2[i][j] = f32x4{0.f, 0.f, 0.f, 0.f};
        }

    auto STAGE = [&](int b, int k0) {           // 6 loads/thread
        #pragma unroll
        for (int p = 0; p < 2; ++p) {
            int idx = p * 256 + tid;
            int row = idx >> 2;
            int ch  = 8 * ((idx & 3) ^ ((idx >> 3) & 3));
            GLD16(A  + (size_t)(bm + row) * K + k0 + ch, sA[b]  + idx * 8);
            GLD16(W1 + (size_t)(bn + row) * K + k0 + ch, sB1[b] + idx * 8);
            GLD16(W2 + (size_t)(bn + row) * K + k0 + ch, sB2[b] + idx * 8);
        }
    };

    const int T = K >> 5;
    STAGE(0, 0);
    if (T > 1) STAGE(1, 32);
    int b0 = 0, b1 = 1, b2 = 2;
    for (int kt = 0; kt < T; ++kt) {
        if (kt + 2 < T) STAGE(b2, (kt + 2) * 32);
        int ahead = (kt + 2 < T) ? 2 : ((kt + 1 < T) ? 1 : 0);
        WAIT_BAR(ahead, "12", "6");
        const bf16_t* sAr  = sA[b0];
        const bf16_t* sB1r = sB1[b0];
        const bf16_t* sB2r = sB2[b0];
        bf16x8 af[4], f1[4], f2[4];
        #pragma unroll
        for (int i = 0; i < 4; ++i)
            af[i] = *(const bf16x8*)(sAr + (wm + i * 16 + lr) * 32 + 8 * (kg ^ rsw));
        #pragma unroll
        for (int j = 0; j < 4; ++j) {
            f1[j] = *(const bf16x8*)(sB1r + (wn + j * 16 + lr) * 32 + 8 * (kg ^ rsw));
            f2[j] = *(const bf16x8*)(sB2r + (wn + j * 16 + lr) * 32 + 8 * (kg ^ rsw));
        }
        #pragma unroll
        for (int i = 0; i < 4; ++i)
            #pragma unroll
            for (int j = 0; j < 4; ++j) {
                acc1[i][j] = __builtin_amdgcn_mfma_f32_16x16x32_bf16(
                    af[i], f1[j], acc1[i][j], 0, 0, 0);
                acc2[i][j] = __builtin_amdgcn_mfma_f32_16x16x32_bf16(
                    af[i], f2[j], acc2[i][j], 0, 0, 0);
            }
        BAR_LGKM();
        int t = b0; b0 = b1; b1 = b2; b2 = t;
    }

    #pragma unroll
    for (int i = 0; i < 4; ++i) {
        #pragma unroll
        for (int j = 0; j < 4; ++j) {
            #pragma unroll
            for (int rr = 0; rr < 4; ++rr) {
                int m = bm + wm + i * 16 + kg * 4 + rr;
                int n = bn + wn + j * 16 + lr;
                float v1 = acc1[i][j][rr], v2 = acc2[i][j][rr];
                out[(size_t)m * N + n] = (bf16_t)(v1 / (1.f + __expf(-v1)) * v2);
            }
        }
    }
}

// ---------------------------------------------------------------------------
// Expert segment offset from cnt[]
// ---------------------------------------------------------------------------
__device__ __forceinline__ int seg_off(const int* cnt, int e)
{
    int r = 0;
    #pragma unroll
    for (int k = 0; k < 8; ++k) if (k < e) r += (cnt[k] + 127) & ~127;
    return r;
}

// ---------------------------------------------------------------------------
// Grouped gathered GLU for routed experts, BK=32 3-buf 2-deep (72KB).
// Grid (8, 256).
// ---------------------------------------------------------------------------
__global__ __launch_bounds__(256) void glu_gather(
    const bf16_t* __restrict__ A, const bf16_t* __restrict__ W1,
    const bf16_t* __restrict__ W2, const int* __restrict__ tok_list,
    const int* __restrict__ cnt, bf16_t* __restrict__ h)
{
    const int e = blockIdx.y >> 5, t = blockIdx.y & 31;
    const int ce = cnt[e];
    if (t * 128 >= ce) return;
    const int hbase = seg_off(cnt, e) + t * 128;
    const bf16_t* W1e = W1 + (size_t)e * 1048576;
    const bf16_t* W2e = W2 + (size_t)e * 1048576;

    __shared__ __align__(16) bf16_t sA[3][128 * 32];
    __shared__ __align__(16) bf16_t sB1[3][128 * 32];
    __shared__ __align__(16) bf16_t sB2[3][128 * 32];
    const int tid  = threadIdx.x;
    const int bn   = blockIdx.x * 128;
    const int lane = tid & 63;
    const int wv   = tid >> 6;
    const int wm   = (wv >> 1) * 64, wn = (wv & 1) * 64;
    const int lr   = lane & 15;
    const int kg   = lane >> 4;
    const int rsw  = (lr >> 1) & 3;

    int tok2[2];
    #pragma unroll
    for (int p = 0; p < 2; ++p)
        tok2[p] = tok_list[e * 4096 + t * 128 + ((p * 256 + tid) >> 2)];

    f32x4 acc1[4][4], acc2[4][4];
    #pragma unroll
    for (int i = 0; i < 4; ++i)
        #pragma unroll
        for (int j = 0; j < 4; ++j) {
            acc1[i][j] = f32x4{0.f, 0.f, 0.f, 0.f};
            acc2[i][j] = f32x4{0.f, 0.f, 0.f, 0.f};
        }

    auto STAGE = [&](int b, int k0) {           // 6 loads/thread
        #pragma unroll
        for (int p = 0; p < 2; ++p) {
            int idx = p * 256 + tid;
            int row = idx >> 2;
            int ch  = 8 * ((idx & 3) ^ ((idx >> 3) & 3));
            GLD16(A   + (size_t)tok2[p] * 1024 + k0 + ch,    sA[b]  + idx * 8);
            GLD16(W1e + (size_t)(bn + row) * 1024 + k0 + ch, sB1[b] + idx * 8);
            GLD16(W2e + (size_t)(bn + row) * 1024 + k0 + ch, sB2[b] + idx * 8);
        }
    };

    STAGE(0, 0);
    STAGE(1, 32);
    int b0 = 0, b1 = 1, b2 = 2;
    for (int kt = 0; kt < 32; ++kt) {
        if (kt + 2 < 32) STAGE(b2, (kt + 2) * 32);
        int ahead = (kt + 2 < 32) ? 2 : ((kt + 1 < 32) ? 1 : 0);
        WAIT_BAR(ahead, "12", "6");
        const bf16_t* sAr  = sA[b0];
        const bf16_t* sB1r = sB1[b0];
        const bf16_t* sB2r = sB2[b0];
        bf16x8 af[4], f1[4], f2[4];
        #pragma unroll
        for (int i = 0; i < 4; ++i)
            af[i] = *(const bf16x8*)(sAr + (wm + i * 16 + lr) * 32 + 8 * (kg ^ rsw));
        #pragma unroll
        for (int j = 0; j < 4; ++j) {
            f1[j] = *(const bf16x8*)(sB1r + (wn + j * 16 + lr) * 32 + 8 * (kg ^ rsw));
            f2[j] = *(const bf16x8*)(sB2r + (wn + j * 16 + lr) * 32 + 8 * (kg ^ rsw));
        }
        #pragma unroll
        for (int i = 0; i < 4; ++i)
            #pragma unroll
            for (int j = 0; j < 4; ++j) {
                acc1[i][j] = __builtin_amdgcn_mfma_f32_16x16x32_bf16(
                    af[i], f1[j], acc1[i][j], 0, 0, 0);
                acc2[i][j] = __builtin_amdgcn_mfma_f32_16x16x32_bf16(
                    af[i], f2[j], acc2[i][j], 0, 0, 0);
            }
        BAR_LGKM();
        int tt = b0; b0 = b1; b1 = b2; b2 = tt;
    }

    #pragma unroll
    for (int i = 0; i < 4; ++i) {
        #pragma unroll
        for (int j = 0; j < 4; ++j) {
            #pragma unroll
            for (int rr = 0; rr < 4; ++rr) {
                int rl = wm + i * 16 + kg * 4 + rr;
                int n  = bn + wn + j * 16 + lr;
                float v1 = acc1[i][j][rr], v2 = acc2[i][j][rr];
                h[(size_t)(hbase + rl) * 1024 + n] =
                    (bf16_t)(v1 / (1.f + __expf(-v1)) * v2);
            }
        }
    }
}

// ---------------------------------------------------------------------------
// Grouped routed down-proj, BK=32 3-buf 2-deep, weighted scatter-add.
// ---------------------------------------------------------------------------
__global__ __launch_bounds__(256) void down_gather(
    const bf16_t* __restrict__ h, const bf16_t* __restrict__ Wp,
    const int* __restrict__ tok_list, const float* __restrict__ w_list,
    const int* __restrict__ cnt, float* __restrict__ out)
{
    const int e = blockIdx.y >> 5, t = blockIdx.y & 31;
    const int ce = cnt[e];
    if (t * 128 >= ce) return;
    const int hbase = seg_off(cnt, e) + t * 128;
    const bf16_t* We = Wp + (size_t)e * 1048576;

    __shared__ __align__(16) bf16_t sA[3][128 * 32];
    __shared__ __align__(16) bf16_t sB[3][128 * 32];
    const int tid  = threadIdx.x;
    const int bn   = blockIdx.x * 128;
    const int lane = tid & 63;
    const int wv   = tid >> 6;
    const int wm   = (wv >> 1) * 64, wn = (wv & 1) * 64;
    const int lr   = lane & 15;
    const int kg   = lane >> 4;
    const int rsw  = (lr >> 1) & 3;

    f32x4 acc[4][4];
    #pragma unroll
    for (int i = 0; i < 4; ++i)
        #pragma unroll
        for (int j = 0; j < 4; ++j)
            acc[i][j] = f32x4{0.f, 0.f, 0.f, 0.f};

    auto STAGE = [&](int b, int k0) {           // 4 loads/thread
        #pragma unroll
        for (int p = 0; p < 2; ++p) {
            int idx = p * 256 + tid;
            int row = idx >> 2;
            int ch  = 8 * ((idx & 3) ^ ((idx >> 3) & 3));
            GLD16(h  + (size_t)(hbase + row) * 1024 + k0 + ch, sA[b] + idx * 8);
            GLD16(We + (size_t)(bn + row) * 1024 + k0 + ch,    sB[b] + idx * 8);
        }
    };

    STAGE(0, 0);
    STAGE(1, 32);
    int b0 = 0, b1 = 1, b2 = 2;
    for (int kt = 0; kt < 32; ++kt) {
        if (kt + 2 < 32) STAGE(b2, (kt + 2) * 32);
        int ahead = (kt + 2 < 32) ? 2 : ((kt + 1 < 32) ? 1 : 0);
        WAIT_BAR(ahead, "8", "4");
        const bf16_t* sAr = sA[b0];
        const bf16_t* sBr = sB[b0];
        bf16x8 af[4], bfr[4];
        #pragma unroll
        for (int i = 0; i < 4; ++i)
            af[i] = *(const bf16x8*)(sAr + (wm + i * 16 + lr) * 32 + 8 * (kg ^ rsw));
        #pragma unroll
        for (int j = 0; j < 4; ++j)
            bfr[j] = *(const bf16x8*)(sBr + (wn + j * 16 + lr) * 32 + 8 * (kg ^ rsw));
        #pragma unroll
        for (int i = 0; i < 4; ++i)
            #pragma unroll
            for (int j = 0; j < 4; ++j)
                acc[i][j] = __builtin_amdgcn_mfma_f32_16x16x32_bf16(
                    af[i], bfr[j], acc[i][j], 0, 0, 0);
        BAR_LGKM();
        int tt = b0; b0 = b1; b1 = b2; b2 = tt;
    }

    #pragma unroll
    for (int i = 0; i < 4; ++i) {
        #pragma unroll
        for (int rr = 0; rr < 4; ++rr) {
            int g = t * 128 + wm + i * 16 + kg * 4 + rr;
            if (g < ce) {
                int   tok = tok_list[e * 4096 + g];
                float wgt = w_list[e * 4096 + g];
                #pragma unroll
                for (int j = 0; j < 4; ++j) {
                    int n = bn + wn + j * 16 + lr;
                    atomicAdd(&out[(size_t)tok * 1024 + n], wgt * acc[i][j][rr]);
                }
            }
        }
    }
}

// ---------------------------------------------------------------------------
// RMSNorm: fp32 src -> bf16 dst, row length 1024 (norm1)
// ---------------------------------------------------------------------------
__global__ __launch_bounds__(256) void rmsnorm_k(
    const float* __restrict__ src, const float* __restrict__ w,
    bf16_t* __restrict__ dst)
{
    const int row = blockIdx.x, tid = threadIdx.x;
    float4 t4 = *((const float4*)src + (size_t)row * 256 + tid);
    float ssum = t4.x*t4.x + t4.y*t4.y + t4.z*t4.z + t4.w*t4.w;
    #pragma unroll
    for (int off = 32; off > 0; off >>= 1) ssum += __shfl_down(ssum, off);
    __shared__ float red[4];
    if ((tid & 63) == 0) red[tid >> 6] = ssum;
    __syncthreads();
    float total = red[0] + red[1] + red[2] + red[3];
    float rms = rsqrtf(total * (1.0f / 1024.0f) + 1e-6f);
    float4 w4 = *((const float4*)w + tid);
    bf16x4 o4;
    o4[0] = (bf16_t)(t4.x * rms * w4.x);
    o4[1] = (bf16_t)(t4.y * rms * w4.y);
    o4[2] = (bf16_t)(t4.z * rms * w4.z);
    o4[3] = (bf16_t)(t4.w * rms * w4.w);
    *((bf16x4*)dst + (size_t)row * 256 + tid) = o4;
}

// ---------------------------------------------------------------------------
// Fused RMSNorm + MoE gate (fp32 logits in-register; no atomics).
// ---------------------------------------------------------------------------
__global__ __launch_bounds__(256) void rmsnorm_gate_k(
    const float* __restrict__ src, const float* __restrict__ w,
    const float* __restrict__ gw, bf16_t* __restrict__ dst,
    float* __restrict__ scores, int* __restrict__ topi,
    float* __restrict__ topw)
{
    const int row = blockIdx.x, tid = threadIdx.x;
    float4 t4 = *((const float4*)src + (size_t)row * 256 + tid);
    float ssum = t4.x*t4.x + t4.y*t4.y + t4.z*t4.z + t4.w*t4.w;
    #pragma unroll
    for (int off = 32; off > 0; off >>= 1) ssum += __shfl_down(ssum, off);
    __shared__ float red[4];
    if ((tid & 63) == 0) red[tid >> 6] = ssum;
    __syncthreads();
    float total = red[0] + red[1] + red[2] + red[3];
    float rms = rsqrtf(total * (1.0f / 1024.0f) + 1e-6f);
    float4 w4 = *((const float4*)w + tid);
    float4 f4;
    f4.x = t4.x * rms * w4.x;
    f4.y = t4.y * rms * w4.y;
    f4.z = t4.z * rms * w4.z;
    f4.w = t4.w * rms * w4.w;
    bf16x4 o4;
    o4[0] = (bf16_t)f4.x; o4[1] = (bf16_t)f4.y;
    o4[2] = (bf16_t)f4.z; o4[3] = (bf16_t)f4.w;
    *((bf16x4*)dst + (size_t)row * 256 + tid) = o4;

    float a[8];
    #pragma unroll
    for (int e = 0; e < 8; ++e) {
        float4 g4 = *((const float4*)(gw + (size_t)e * 1024) + tid);
        a[e] = f4.x * g4.x + f4.y * g4.y + f4.z * g4.z + f4.w * g4.w;
    }
    #pragma unroll
    for (int e = 0; e < 8; ++e)
        #pragma unroll
        for (int off = 32; off > 0; off >>= 1) a[e] += __shfl_down(a[e], off);
    __shared__ float gred[4][8];
    if ((tid & 63) == 0)
        #pragma unroll
        for (int e = 0; e < 8; ++e) gred[tid >> 6][e] = a[e];
    __syncthreads();
    if (tid == 0) {
        float lg[8];
        #pragma unroll
        for (int e = 0; e < 8; ++e)
            lg[e] = gred[0][e] + gred[1][e] + gred[2][e] + gred[3][e];
        #pragma unroll
        for (int e = 0; e < 8; ++e) scores[(size_t)row * 8 + e] = lg[e];
        float mx = lg[0];
        #pragma unroll
        for (int e = 1; e < 8; ++e) mx = fmaxf(mx, lg[e]);
        float p[8], sum = 0.f;
        #pragma unroll
        for (int e = 0; e < 8; ++e) { p[e] = __expf(lg[e] - mx); sum += p[e]; }
        float inv = 1.0f / sum;
        #pragma unroll
        for (int e = 0; e < 8; ++e) p[e] *= inv;
        int i1 = 0;
        #pragma unroll
        for (int e = 1; e < 8; ++e) if (p[e] > p[i1]) i1 = e;
        int i2 = (i1 == 0) ? 1 : 0;
        #pragma unroll
        for (int e = 0; e < 8; ++e) if (e != i1 && p[e] > p[i2]) i2 = e;
        topi[row] = i1 | (i2 << 8);
        topw[row * 2]     = p[i1];
        topw[row * 2 + 1] = p[i2];
    }
}

// ---------------------------------------------------------------------------
// Build per-expert token lists WITHOUT atomics (one block per expert).
// ---------------------------------------------------------------------------
__global__ __launch_bounds__(256) void build_lists_k(
    const int* __restrict__ topi, const float* __restrict__ topw,
    int* __restrict__ tok_list, float* __restrict__ w_list,
    int* __restrict__ cnt)
{
    const int e = blockIdx.x;
    const int tid = threadIdx.x, lane = tid & 63, wv = tid >> 6;
    __shared__ int wc[4];
    int base = 0;
    for (int t0 = 0; t0 < 4096; t0 += 256) {
        int tok = t0 + tid;
        int ti = topi[tok];
        int i1 = ti & 255, i2 = (ti >> 8) & 255;
        bool m = (i1 == e) || (i2 == e);
        unsigned long long b = __ballot(m);
        if (lane == 0) wc[wv] = __popcll(b);
        __syncthreads();
        int pos = base;
        #pragma unroll
        for (int k = 0; k < 4; ++k) if (k < wv) pos += wc[k];
        pos += __popcll(b & ((1ull << lane) - 1ull));
        if (m) {
            tok_list[e * 4096 + pos] = tok;
            w_list[e * 4096 + pos]   = (i1 == e) ? topw[tok * 2] : topw[tok * 2 + 1];
        }
        base += wc[0] + wc[1] + wc[2] + wc[3];
        __syncthreads();
    }
    int padded = (base + 127) & ~127;
    for (int p = base + tid; p < padded; p += 256) tok_list[e * 4096 + p] = 0;
    if (tid == 0) cnt[e] = base;
}

// ---------------------------------------------------------------------------
// RoPE in-place on qkv buffer (4096 x 1536)
// ---------------------------------------------------------------------------
__global__ __launch_bounds__(256) void rope_all_k(
    bf16_t* __restrict__ qkv, const float* __restrict__ fc)
{
    int idx = blockIdx.x * 256 + threadIdx.x;
    int pr = idx & 31;
    int hn = idx >> 5;
    int h  = hn % 20;
    int n  = hn / 20;
    int tpos = n & 1023;
    const float* f = fc + ((size_t)tpos * 32 + pr) * 2;
    float c = f[0], s = f[1];
    int col = (h < 16) ? h * 64 : 1024 + (h - 16) * 64;
    size_t base = (size_t)n * LQKV + col + pr * 2;
    float x0 = (float)qkv[base], x1 = (float)qkv[base + 1];
    qkv[base]     = (bf16_t)(x0 * c - x1 * s);
    qkv[base + 1] = (bf16_t)(x1 * c + x0 * s);
}

// ---------------------------------------------------------------------------
// V transpose: qkv V-part (cols 1280..1535) -> vt [(b*4+kvh)*64+d][1024]
// ---------------------------------------------------------------------------
__global__ __launch_bounds__(256) void transpose_v(
    const bf16_t* __restrict__ qkv, bf16_t* __restrict__ vt)
{
    __shared__ bf16_t tile[64][72];
    const int tt = blockIdx.x, kvh = blockIdx.y, b = blockIdx.z;
    const int tid = threadIdx.x;
    {
        int r = tid >> 2, c = (tid & 3) * 16;
        const bf16_t* src = qkv + ((size_t)(b * 1024 + tt * 64 + r)) * LQKV
                            + 1280 + kvh * 64 + c;
        bf16x8 v0 = *(const bf16x8*)src;
        bf16x8 v1 = *(const bf16x8*)(src + 8);
        *(bf16x8*)&tile[r][c] = v0;
        *(bf16x8*)&tile[r][c + 8] = v1;
    }
    __syncthreads();
    {
        int d = tid >> 2, t4 = (tid & 3) * 16;
        bf16_t* dst = vt + ((size_t)((b * 4 + kvh) * 64 + d)) * 1024 + tt * 64 + t4;
        bf16x8 o0, o1;
        #pragma unroll
        for (int u = 0; u < 8; ++u) {
            o0[u] = tile[t4 + u][d];
            o1[u] = tile[t4 + 8 + u][d];
        }
        *(bf16x8*)dst = o0;
        *(bf16x8*)(dst + 8) = o1;
    }
}

// ---------------------------------------------------------------------------
// MFMA flash attention, causal GQA. Grid (qt=16, h=16, b=4), 256 thr = 4 waves.
// ---------------------------------------------------------------------------
__global__ __launch_bounds__(256) void attn_mfma(
    const bf16_t* __restrict__ qkv, const bf16_t* __restrict__ vt,
    bf16_t* __restrict__ ob)
{
    const int qt = blockIdx.x, h = blockIdx.y, b = blockIdx.z;
    const int kvh = h >> 2;
    __shared__ __align__(16) bf16_t sK[64 * 64];
    __shared__ __align__(16) bf16_t sVt[64 * 64];
    __shared__ __align__(16) bf16_t sP[64 * 72];
    const int tid  = threadIdx.x;
    const int w    = tid >> 6;
    const int lane = tid & 63;
    const int lr   = lane & 15;
    const int kg   = lane >> 4;
    const int swz  = (lr & 7) << 3;

    bf16x8 qf[2];
    {
        const bf16_t* qrow = qkv + ((size_t)(b * 1024 + qt * 64 + w * 16 + lr)) * LQKV
                             + h * 64;
        qf[0] = *(const bf16x8*)(qrow + kg * 8);
        qf[1] = *(const bf16x8*)(qrow + 32 + kg * 8);
    }
    float m_run[4], l_run[4];
    f32x4 o_acc[4];
    #pragma unroll
    for (int rr = 0; rr < 4; ++rr) { m_run[rr] = -1.0e30f; l_run[rr] = 0.f; }
    #pragma unroll
    for (int dt = 0; dt < 4; ++dt) o_acc[dt] = f32x4{0.f, 0.f, 0.f, 0.f};

    for (int kt = 0; kt <= qt; ++kt) {
        #pragma unroll
        for (int p = 0; p < 2; ++p) {
            int idx = p * 256 + tid;
            int row = idx >> 3;
            int chs = ((idx & 7) * 8) ^ ((row & 7) << 3);
            GLD16(qkv + ((size_t)(b * 1024 + kt * 64 + row)) * LQKV
                      + 1024 + kvh * 64 + chs, sK + idx * 8);
            GLD16(vt + ((size_t)((b * 4 + kvh) * 64 + row)) * 1024 + kt * 64 + chs,
                  sVt + idx * 8);
        }
        __syncthreads();

        f32x4 sfr[4];
        #pragma unroll
        for (int j = 0; j < 4; ++j) {
            sfr[j] = f32x4{0.f, 0.f, 0.f, 0.f};
            #pragma unroll
            for (int ks = 0; ks < 2; ++ks) {
                bf16x8 bf = *(const bf16x8*)(sK + (j * 16 + lr) * 64 +
                                             ((ks * 32 + kg * 8) ^ swz));
                sfr[j] = __builtin_amdgcn_mfma_f32_16x16x32_bf16(qf[ks], bf, sfr[j], 0, 0, 0);
            }
        }
        const int rowg = qt * 64 + w * 16 + kg * 4;
        float mnew[4];
        #pragma unroll
        for (int rr = 0; rr < 4; ++rr) mnew[rr] = m_run[rr];
        #pragma unroll
        for (int j = 0; j < 4; ++j) {
            int colg = kt * 64 + j * 16 + lr;
            #pragma unroll
            for (int rr = 0; rr < 4; ++rr) {
                float s = sfr[j][rr] * 0.125f;
                if (colg > rowg + rr) s = -1.0e30f;
                sfr[j][rr] = s;
                mnew[rr] = fmaxf(mnew[rr], s);
            }
        }
        #pragma unroll
        for (int off = 1; off < 16; off <<= 1)
            #pragma unroll
            for (int rr = 0; rr < 4; ++rr)
                mnew[rr] = fmaxf(mnew[rr], __shfl_xor(mnew[rr], off, 64));
        float alpha[4], lpart[4];
        #pragma unroll
        for (int rr = 0; rr < 4; ++rr) {
            alpha[rr] = __expf(m_run[rr] - mnew[rr]);
            lpart[rr] = 0.f;
        }
        #pragma unroll
        for (int j = 0; j < 4; ++j)
            #pragma unroll
            for (int rr = 0; rr < 4; ++rr) {
                float p = __expf(sfr[j][rr] - mnew[rr]);
                sfr[j][rr] = p;
                lpart[rr] += p;
            }
        #pragma unroll
        for (int j = 0; j < 4; ++j)
            #pragma unroll
            for (int rr = 0; rr < 4; ++rr)
                sP[(w * 16 + kg * 4 + rr) * 72 + j * 16 + lr] = (bf16_t)sfr[j][rr];
        #pragma unroll
        for (int off = 1; off < 16; off <<= 1)
            #pragma unroll
            for (int rr = 0; rr < 4; ++rr)
                lpart[rr] += __shfl_xor(lpart[rr], off, 64);
        #pragma unroll
        for (int rr = 0; rr < 4; ++rr) {
            l_run[rr] = l_run[rr] * alpha[rr] + lpart[rr];
            m_run[rr] = mnew[rr];
        }
        #pragma unroll
        for (int dt = 0; dt < 4; ++dt)
            #pragma unroll
            for (int rr = 0; rr < 4; ++rr)
                o_acc[dt][rr] *= alpha[rr];
        #pragma unroll
        for (int ks = 0; ks < 2; ++ks) {
            bf16x8 af = *(const bf16x8*)(sP + (w * 16 + lr) * 72 + ks * 32 + kg * 8);
            #pragma unroll
            for (int dt = 0; dt < 4; ++dt) {
                bf16x8 bf = *(const bf16x8*)(sVt + (dt * 16 + lr) * 64 +
                                             ((ks * 32 + kg * 8) ^ swz));
                o_acc[dt] = __builtin_amdgcn_mfma_f32_16x16x32_bf16(af, bf, o_acc[dt], 0, 0, 0);
            }
        }
        __syncthreads();
    }

    float inv[4];
    #pragma unroll
    for (int rr = 0; rr < 4; ++rr) inv[rr] = 1.0f / l_run[rr];
    #pragma unroll
    for (int dt = 0; dt < 4; ++dt)
        #pragma unroll
        for (int rr = 0; rr < 4; ++rr) {
            int tok = qt * 64 + w * 16 + kg * 4 + rr;
            ob[((size_t)(b * 1024 + tok)) * 1024 + h * 64 + dt * 16 + lr] =
                (bf16_t)(o_acc[dt][rr] * inv[rr]);
        }
}

// ---------------------------------------------------------------------------
extern "C" void kernel_launch(void* const* d_in, const int* in_sizes, int n_in,
                              void* d_out, int out_size, void* d_ws, size_t ws_size,
                              hipStream_t stream)
{
    const float* x   = (const float*)d_in[0];
    const float* fc  = (const float*)d_in[1];
    const float* n1w = (const float*)d_in[4];
    const float* wq  = (const float*)d_in[5];
    const float* wk  = (const float*)d_in[6];
    const float* wv  = (const float*)d_in[7];
    const float* wo  = (const float*)d_in[8];
    const float* n2w = (const float*)d_in[9];
    const float* gw  = (const float*)d_in[10];
    const float* ew1 = (const float*)d_in[11];
    const float* ew2 = (const float*)d_in[12];
    const float* ewp = (const float*)d_in[13];
    const float* sw1 = (const float*)d_in[14];
    const float* sw2 = (const float*)d_in[15];
    const float* swp = (const float*)d_in[16];

    // ---- workspace (peak ~93 MB; phase-aliased) ----
    const size_t MB = 1024 * 1024;
    char* ws = (char*)d_ws;
    bf16_t* xnb  = (bf16_t*)(ws + 0);         // [0,8)   xn / xn2 bf16
    float*  x1   = (float*) (ws + 8 * MB);    // [8,24)  residual fp32 (dead after gate)
    bf16_t* ew2b = (bf16_t*)(ws + 8 * MB);    //         ... then expert W2 bf16
    bf16_t* h    = (bf16_t*)(ws + 24 * MB);   // [24,42) routed GLU out (9216x1024)
    char*   lists= ws + 42 * MB;              // [42,43) routing lists
    int*    tok_list = (int*)lists;
    float*  w_list   = (float*)(lists + 131072);
    int*    cnt      = (int*)(lists + 262144);
    int*    topi     = (int*)(lists + 262400);
    float*  topw     = (float*)(lists + 278784);
    bf16_t* sw1b = (bf16_t*)(ws + 43 * MB);   // [43,47) shared W1 bf16
    bf16_t* sw2b = (bf16_t*)(ws + 47 * MB);   // [47,51) shared W2 bf16
    bf16_t* swpb = (bf16_t*)(ws + 51 * MB);   // [51,55) shared Wp bf16
    char*   slotA= ws + 55 * MB;              // [55,71) attn weights -> shared hb
    bf16_t* hb   = (bf16_t*)slotA;            //         shared GLU out (4096x2048)
    bf16_t* qkv  = (bf16_t*)(ws + 71 * MB);   // [71,83) fused QKV (4096x1536)
    bf16_t* ob   = (bf16_t*)(ws + 83 * MB);   // [83,91) attn out
    bf16_t* vt   = (bf16_t*)(ws + 91 * MB);   // [91,93) V transposed
    bf16_t* ew1b = (bf16_t*)(ws + 71 * MB);   // [71,87) expert W1 (qkv/ob dead)
    bf16_t* ewpb = (bf16_t*)(ws + 71 * MB);   // [71,87) expert Wp (after GLU)

    float* outp   = (float*)d_out;
    float* scores = outp + (size_t)4096 * 1024;

    auto gemm = [&](const bf16_t* A, const bf16_t* W, int M, int N, int K, int ldw,
                    int mode, float* oF, bf16_t* oB, const float* res, float* oF2) {
        gemm_bt<<<dim3(N / 128, M / 128), 256, 0, stream>>>(
            A, W, M, N, K, ldw, mode, oF, oB, res, oF2);
    };

    // ---- batched weight conversion #1: attn (QKV contiguous) + shared ----
    bf16_t* wqb = (bf16_t*)slotA;             // [wqb..] 1536x1024 contiguous
    bf16_t* wkb = wqb + 1048576;
    bf16_t* wvb = wkb + 262144;
    bf16_t* wob = wvb + 262144;
    {
        Cvt8 j;
        j.s[0]=wq;  j.d[0]=wqb;  j.s[1]=wk;  j.d[1]=wkb;
        j.s[2]=wv;  j.d[2]=wvb;  j.s[3]=wo;  j.d[3]=wob;
        j.s[4]=sw1; j.d[4]=sw1b; j.s[5]=sw2; j.d[5]=sw2b;
        j.s[6]=swp; j.d[6]=swpb; j.s[7]=nullptr; j.d[7]=nullptr;
        int sz[7] = {1024, 256, 256, 1024, 2048, 2048, 2048};
        j.cum[0] = 0;
        for (int k = 0; k < 7; ++k) j.cum[k + 1] = j.cum[k] + sz[k];
        j.cum[8] = j.cum[7];
        j.nseg = 7;
        convert_multi_k<<<j.cum[7], 256, 0, stream>>>(j);
    }

    // ---- attention ----
    rmsnorm_k<<<4096, 256, 0, stream>>>(x, n1w, xnb);
    gemm(xnb, wqb, 4096, LQKV, 1024, 1024, 1, nullptr, qkv, nullptr, nullptr);
    rope_all_k<<<(4096 * 20 * 32) / 256, 256, 0, stream>>>(qkv, fc);
    transpose_v<<<dim3(16, 4, 4), 256, 0, stream>>>(qkv, vt);
    attn_mfma<<<dim3(16, 16, 4), 256, 0, stream>>>(qkv, vt, ob);
    gemm(ob, wob, 4096, 1024, 1024, 1024, 2, x1, nullptr, x, outp);

    // ---- MoE: fused norm2+gate, atomics-free list build ----
    rmsnorm_gate_k<<<4096, 256, 0, stream>>>(x1, n2w, gw, xnb, scores, topi, topw);
    build_lists_k<<<8, 256, 0, stream>>>(topi, topw, tok_list, w_list, cnt);

    // ---- batched weight conversion #2: expert W1 + W2 ----
    {
        Cvt8 j;
        j.s[0]=ew1; j.d[0]=ew1b; j.s[1]=ew2; j.d[1]=ew2b;
        for (int k = 2; k < 8; ++k) { j.s[k]=nullptr; j.d[k]=nullptr; }
        j.cum[0] = 0; j.cum[1] = 8192; j.cum[2] = 16384;
        for (int k = 3; k < 9; ++k) j.cum[k] = 16384;
        j.nseg = 2;
        convert_multi_k<<<16384, 256, 0, stream>>>(j);
    }

    // ---- GLU: shared (dense) then routed (grouped gather) ----
    gemm_glu<<<dim3(16, 32), 256, 0, stream>>>(xnb, sw1b, sw2b, 4096, 2048, 1024, hb);
    glu_gather<<<dim3(8, 256), 256, 0, stream>>>(xnb, ew1b, ew2b, tok_list, cnt, h);

    // ---- expert Wp conversion (ew1b dead after GLU) ----
    convert_k<<<8192, 256, 0, stream>>>(ewp, ewpb);

    // ---- down-proj: shared (outp += hb@swp^T, non-atomic), then routed ----
    gemm(hb, swpb, 4096, 1024, 2048, 2048, 3, outp, nullptr, nullptr, nullptr);
    down_gather<<<dim3(8, 256), 256, 0, stream>>>(h, ewpb, tok_list, w_list, cnt, outp);

    (void)in_sizes; (void)n_in; (void)out_size; (void)ws_size;
}

// Round 8
// 617.250 us; speedup vs baseline: 1.0346x; 1.0346x over previous
//
#include <hip/hip_runtime.h>

// ---------------------------------------------------------------------------
// Transformer block on MI355X. Inputs fp32, output fp32.
// GEMMs + attention via MFMA 16x16x32 bf16. Gate FUSED into rmsnorm2 (fp32
// logits). Routing lists atomics-free (ballot). MoE sparse top-2.
// R8: per-kernel best-of breeding + XCD-expert alignment.
//  - gemm_bt / gemm_glu / down_gather: restored to r5 form (BK=64 2-buf
//    drain) -- r6/r7 showed BK=32 counted hurts the 2-tensor/dense kernels.
//  - glu_gather: r7 form (BK=32 3-buf counted vmcnt) -- its best (96.5us).
//  - NEW: glu_gather/down_gather decode expert from linear%8 so expert e's
//    blocks land on XCD e (dispatch round-robins linear id over XCDs).
//    r7 PMC: FETCH 76.7MB vs 42MB compulsory (1.8x refetch), MfmaUtil 14%,
//    75% dead cycles -> L2 thrash (old mapping: 12MB/XCD on 4MB L2).
//    Expert-aligned: W1e+W2e (4MB) + A_e (~1.2MB) fits. Pure permutation.
// Workspace peak ~93 MB (phase-aliased).
// ---------------------------------------------------------------------------

typedef __bf16 bf16_t;
typedef __bf16 bf16x8 __attribute__((ext_vector_type(8)));
typedef __bf16 bf16x4 __attribute__((ext_vector_type(4)));
typedef float  f32x4  __attribute__((ext_vector_type(4)));

#define LQKV 1536

#define GLD16(gp, lp) __builtin_amdgcn_global_load_lds(                         \
    (const __attribute__((address_space(1))) void*)(gp),                        \
    (__attribute__((address_space(3))) void*)(lp), 16, 0, 0)

// drain own vmem loads, then block barrier
#define PIPE_BARRIER() do {                                                     \
    asm volatile("s_waitcnt vmcnt(0)" ::: "memory");                            \
    __builtin_amdgcn_s_barrier();                                               \
} while (0)

// counted pre-compute barrier (waits only tile-k loads; deeper stay in flight)
#define WAIT_BAR(ahead, L2s, L1s) do {                                          \
    if ((ahead) == 2)      asm volatile("s_waitcnt vmcnt(" L2s ")" ::: "memory");\
    else if ((ahead) == 1) asm volatile("s_waitcnt vmcnt(" L1s ")" ::: "memory");\
    else                   asm volatile("s_waitcnt vmcnt(0)" ::: "memory");     \
    __builtin_amdgcn_s_barrier();                                               \
} while (0)

// post-compute barrier: LDS reads done (lgkm only -- vmcnt stays in flight)
#define BAR_LGKM() do {                                                         \
    asm volatile("s_waitcnt lgkmcnt(0)" ::: "memory");                          \
    __builtin_amdgcn_s_barrier();                                               \
} while (0)

// ---------------------------------------------------------------------------
// fp32 -> bf16 convert, 4 elems/thread (single tensor)
// ---------------------------------------------------------------------------
__global__ __launch_bounds__(256) void convert_k(
    const float* __restrict__ src, bf16_t* __restrict__ dst)
{
    size_t i = (size_t)blockIdx.x * 256 + threadIdx.x;
    float4 v = *((const float4*)src + i);
    bf16x4 o;
    o[0] = (bf16_t)v.x; o[1] = (bf16_t)v.y; o[2] = (bf16_t)v.z; o[3] = (bf16_t)v.w;
    *((bf16x4*)dst + i) = o;
}

// ---------------------------------------------------------------------------
// Multi-tensor fp32 -> bf16 convert: up to 8 segments in one launch.
// ---------------------------------------------------------------------------
struct Cvt8 {
    const float* s[8];
    bf16_t* d[8];
    int cum[9];
    int nseg;
};

__global__ __launch_bounds__(256) void convert_multi_k(Cvt8 j)
{
    int blk = blockIdx.x;
    int seg = 0;
    while (seg + 1 < j.nseg && blk >= j.cum[seg + 1]) ++seg;
    size_t i = (size_t)(blk - j.cum[seg]) * 256 + threadIdx.x;
    float4 v = *((const float4*)j.s[seg] + i);
    bf16x4 o;
    o[0] = (bf16_t)v.x; o[1] = (bf16_t)v.y; o[2] = (bf16_t)v.z; o[3] = (bf16_t)v.w;
    *((bf16x4*)j.d[seg] + i) = o;
}

// ---------------------------------------------------------------------------
// MFMA GEMM, dbuf+swizzle BK=64 (r5 form -- best measured for this kernel):
// C[m,n] = sum_k A[m,k]*W[n,k]
// mode 0: outF = acc; mode 1: outB = bf16(acc);
// mode 2: outF = acc + resF (and outF2 = same if non-null);
// mode 3: outF += acc (non-atomic RMW)
// ---------------------------------------------------------------------------
__global__ __launch_bounds__(256) void gemm_bt(
    const bf16_t* __restrict__ A, const bf16_t* __restrict__ W,
    int M, int N, int K, int ldw, int mode,
    float* __restrict__ outF, bf16_t* __restrict__ outB,
    const float* __restrict__ resF, float* __restrict__ outF2)
{
    __shared__ __align__(16) bf16_t sA[2][128 * 64];
    __shared__ __align__(16) bf16_t sB[2][128 * 64];
    const int tid  = threadIdx.x;
    const int bm   = blockIdx.y * 128, bn = blockIdx.x * 128;
    const int lane = tid & 63;
    const int wv   = tid >> 6;
    const int wm   = (wv >> 1) * 64, wn = (wv & 1) * 64;
    const int lr   = lane & 15;
    const int kg   = lane >> 4;
    const int swz  = (lr & 7) << 3;

    f32x4 acc[4][4];
    #pragma unroll
    for (int i = 0; i < 4; ++i)
        #pragma unroll
        for (int j = 0; j < 4; ++j)
            acc[i][j] = f32x4{0.f, 0.f, 0.f, 0.f};

    auto STAGE = [&](int b, int k0) {
        #pragma unroll
        for (int p = 0; p < 4; ++p) {
            int idx = p * 256 + tid;
            int row = idx >> 3;
            int ch  = ((idx & 7) * 8) ^ ((row & 7) << 3);
            GLD16(A + (size_t)(bm + row) * K   + k0 + ch, sA[b] + idx * 8);
            GLD16(W + (size_t)(bn + row) * ldw + k0 + ch, sB[b] + idx * 8);
        }
    };

    STAGE(0, 0);
    PIPE_BARRIER();
    int cur = 0;
    for (int k0 = 0; k0 < K; k0 += 64) {
        if (k0 + 64 < K) STAGE(cur ^ 1, k0 + 64);
        #pragma unroll
        for (int ks = 0; ks < 2; ++ks) {
            bf16x8 af[4], bfr[4];
            #pragma unroll
            for (int i = 0; i < 4; ++i)
                af[i] = *(const bf16x8*)(sA[cur] + (wm + i * 16 + lr) * 64 +
                                         ((ks * 32 + kg * 8) ^ swz));
            #pragma unroll
            for (int j = 0; j < 4; ++j)
                bfr[j] = *(const bf16x8*)(sB[cur] + (wn + j * 16 + lr) * 64 +
                                          ((ks * 32 + kg * 8) ^ swz));
            #pragma unroll
            for (int i = 0; i < 4; ++i)
                #pragma unroll
                for (int j = 0; j < 4; ++j)
                    acc[i][j] = __builtin_amdgcn_mfma_f32_16x16x32_bf16(
                        af[i], bfr[j], acc[i][j], 0, 0, 0);
        }
        PIPE_BARRIER();
        cur ^= 1;
    }

    #pragma unroll
    for (int i = 0; i < 4; ++i) {
        #pragma unroll
        for (int j = 0; j < 4; ++j) {
            #pragma unroll
            for (int rr = 0; rr < 4; ++rr) {
                int m = bm + wm + i * 16 + kg * 4 + rr;
                int n = bn + wn + j * 16 + lr;
                size_t o = (size_t)m * N + n;
                float v = acc[i][j][rr];
                if (mode == 0)      outF[o] = v;
                else if (mode == 1) outB[o] = (bf16_t)v;
                else if (mode == 2) {
                    float r = v + resF[o];
                    outF[o] = r;
                    if (outF2) outF2[o] = r;
                } else              outF[o] += v;
            }
        }
    }
}

// ---------------------------------------------------------------------------
// Fused GLU GEMM (dense, shared expert), dbuf BK=64 (r5 form):
// out = bf16(silu(A@W1^T) * (A@W2^T))
// ---------------------------------------------------------------------------
__global__ __launch_bounds__(256) void gemm_glu(
    const bf16_t* __restrict__ A, const bf16_t* __restrict__ W1,
    const bf16_t* __restrict__ W2, int M, int N, int K,
    bf16_t* __restrict__ out)
{
    __shared__ __align__(16) bf16_t sA[2][128 * 64];
    __shared__ __align__(16) bf16_t sB1[2][128 * 64];
    __shared__ __align__(16) bf16_t sB2[2][128 * 64];
    const int tid  = threadIdx.x;
    const int bm   = blockIdx.y * 128, bn = blockIdx.x * 128;
    const int lane = tid & 63;
    const int wv   = tid >> 6;
    const int wm   = (wv >> 1) * 64, wn = (wv & 1) * 64;
    const int lr   = lane & 15;
    const int kg   = lane >> 4;
    const int swz  = (lr & 7) << 3;

    f32x4 acc1[4][4], acc2[4][4];
    #pragma unroll
    for (int i = 0; i < 4; ++i)
        #pragma unroll
        for (int j = 0; j < 4; ++j) {
            acc1[i][j] = f32x4{0.f, 0.f, 0.f, 0.f};
            acc2[i][j] = f32x4{0.f, 0.f, 0.f, 0.f};
        }

    auto STAGE = [&](int b, int k0) {
        #pragma unroll
        for (int p = 0; p < 4; ++p) {
            int idx = p * 256 + tid;
            int row = idx >> 3;
            int ch  = ((idx & 7) * 8) ^ ((row & 7) << 3);
            GLD16(A  + (size_t)(bm + row) * K + k0 + ch, sA[b]  + idx * 8);
            GLD16(W1 + (size_t)(bn + row) * K + k0 + ch, sB1[b] + idx * 8);
            GLD16(W2 + (size_t)(bn + row) * K + k0 + ch, sB2[b] + idx * 8);
        }
    };

    STAGE(0, 0);
    PIPE_BARRIER();
    int cur = 0;
    for (int k0 = 0; k0 < K; k0 += 64) {
        if (k0 + 64 < K) STAGE(cur ^ 1, k0 + 64);
        #pragma unroll
        for (int ks = 0; ks < 2; ++ks) {
            bf16x8 af[4], b1[4], b2[4];
            #pragma unroll
            for (int i = 0; i < 4; ++i)
                af[i] = *(const bf16x8*)(sA[cur] + (wm + i * 16 + lr) * 64 +
                                         ((ks * 32 + kg * 8) ^ swz));
            #pragma unroll
            for (int j = 0; j < 4; ++j) {
                b1[j] = *(const bf16x8*)(sB1[cur] + (wn + j * 16 + lr) * 64 +
                                         ((ks * 32 + kg * 8) ^ swz));
                b2[j] = *(const bf16x8*)(sB2[cur] + (wn + j * 16 + lr) * 64 +
                                         ((ks * 32 + kg * 8) ^ swz));
            }
            #pragma unroll
            for (int i = 0; i < 4; ++i)
                #pragma unroll
                for (int j = 0; j < 4; ++j) {
                    acc1[i][j] = __builtin_amdgcn_mfma_f32_16x16x32_bf16(
                        af[i], b1[j], acc1[i][j], 0, 0, 0);
                    acc2[i][j] = __builtin_amdgcn_mfma_f32_16x16x32_bf16(
                        af[i], b2[j], acc2[i][j], 0, 0, 0);
                }
        }
        PIPE_BARRIER();
        cur ^= 1;
    }

    #pragma unroll
    for (int i = 0; i < 4; ++i) {
        #pragma unroll
        for (int j = 0; j < 4; ++j) {
            #pragma unroll
            for (int rr = 0; rr < 4; ++rr) {
                int m = bm + wm + i * 16 + kg * 4 + rr;
                int n = bn + wn + j * 16 + lr;
                float v1 = acc1[i][j][rr], v2 = acc2[i][j][rr];
                out[(size_t)m * N + n] = (bf16_t)(v1 / (1.f + __expf(-v1)) * v2);
            }
        }
    }
}

// ---------------------------------------------------------------------------
// Expert segment offset from cnt[]
// ---------------------------------------------------------------------------
__device__ __forceinline__ int seg_off(const int* cnt, int e)
{
    int r = 0;
    #pragma unroll
    for (int k = 0; k < 8; ++k) if (k < e) r += (cnt[k] + 127) & ~127;
    return r;
}

// ---------------------------------------------------------------------------
// Grouped gathered GLU for routed experts, BK=32 3-buf 2-deep counted (r7
// form) + XCD-EXPERT decode: expert = linear_block_id % 8 so expert e's
// blocks all land on XCD e (W1e+W2e = 4MB fits that XCD's L2).
// Grid (8, 256) = 2048 blocks; linear id = y*8 + x.
// ---------------------------------------------------------------------------
__global__ __launch_bounds__(256) void glu_gather(
    const bf16_t* __restrict__ A, const bf16_t* __restrict__ W1,
    const bf16_t* __restrict__ W2, const int* __restrict__ tok_list,
    const int* __restrict__ cnt, bf16_t* __restrict__ h)
{
    const int wg = blockIdx.y * 8 + blockIdx.x;   // dispatch-linear id
    const int e  = wg & 7;                        // XCD-aligned expert
    const int r_ = wg >> 3;
    const int t  = r_ & 31;
    const int bn = (r_ >> 5) * 128;
    const int ce = cnt[e];
    if (t * 128 >= ce) return;
    const int hbase = seg_off(cnt, e) + t * 128;
    const bf16_t* W1e = W1 + (size_t)e * 1048576;
    const bf16_t* W2e = W2 + (size_t)e * 1048576;

    __shared__ __align__(16) bf16_t sA[3][128 * 32];
    __shared__ __align__(16) bf16_t sB1[3][128 * 32];
    __shared__ __align__(16) bf16_t sB2[3][128 * 32];
    const int tid  = threadIdx.x;
    const int lane = tid & 63;
    const int wv   = tid >> 6;
    const int wm   = (wv >> 1) * 64, wn = (wv & 1) * 64;
    const int lr   = lane & 15;
    const int kg   = lane >> 4;
    const int rsw  = (lr >> 1) & 3;

    int tok2[2];
    #pragma unroll
    for (int p = 0; p < 2; ++p)
        tok2[p] = tok_list[e * 4096 + t * 128 + ((p * 256 + tid) >> 2)];

    f32x4 acc1[4][4], acc2[4][4];
    #pragma unroll
    for (int i = 0; i < 4; ++i)
        #pragma unroll
        for (int j = 0; j < 4; ++j) {
            acc1[i][j] = f32x4{0.f, 0.f, 0.f, 0.f};
            acc2[i][j] = f32x4{0.f, 0.f, 0.f, 0.f};
        }

    auto STAGE = [&](int b, int k0) {           // 6 loads/thread
        #pragma unroll
        for (int p = 0; p < 2; ++p) {
            int idx = p * 256 + tid;
            int row = idx >> 2;
            int ch  = 8 * ((idx & 3) ^ ((idx >> 3) & 3));
            GLD16(A   + (size_t)tok2[p] * 1024 + k0 + ch,    sA[b]  + idx * 8);
            GLD16(W1e + (size_t)(bn + row) * 1024 + k0 + ch, sB1[b] + idx * 8);
            GLD16(W2e + (size_t)(bn + row) * 1024 + k0 + ch, sB2[b] + idx * 8);
        }
    };

    STAGE(0, 0);
    STAGE(1, 32);
    int b0 = 0, b1 = 1, b2 = 2;
    for (int kt = 0; kt < 32; ++kt) {
        if (kt + 2 < 32) STAGE(b2, (kt + 2) * 32);
        int ahead = (kt + 2 < 32) ? 2 : ((kt + 1 < 32) ? 1 : 0);
        WAIT_BAR(ahead, "12", "6");
        const bf16_t* sAr  = sA[b0];
        const bf16_t* sB1r = sB1[b0];
        const bf16_t* sB2r = sB2[b0];
        bf16x8 af[4], f1[4], f2[4];
        #pragma unroll
        for (int i = 0; i < 4; ++i)
            af[i] = *(const bf16x8*)(sAr + (wm + i * 16 + lr) * 32 + 8 * (kg ^ rsw));
        #pragma unroll
        for (int j = 0; j < 4; ++j) {
            f1[j] = *(const bf16x8*)(sB1r + (wn + j * 16 + lr) * 32 + 8 * (kg ^ rsw));
            f2[j] = *(const bf16x8*)(sB2r + (wn + j * 16 + lr) * 32 + 8 * (kg ^ rsw));
        }
        #pragma unroll
        for (int i = 0; i < 4; ++i)
            #pragma unroll
            for (int j = 0; j < 4; ++j) {
                acc1[i][j] = __builtin_amdgcn_mfma_f32_16x16x32_bf16(
                    af[i], f1[j], acc1[i][j], 0, 0, 0);
                acc2[i][j] = __builtin_amdgcn_mfma_f32_16x16x32_bf16(
                    af[i], f2[j], acc2[i][j], 0, 0, 0);
            }
        BAR_LGKM();
        int tt = b0; b0 = b1; b1 = b2; b2 = tt;
    }

    #pragma unroll
    for (int i = 0; i < 4; ++i) {
        #pragma unroll
        for (int j = 0; j < 4; ++j) {
            #pragma unroll
            for (int rr = 0; rr < 4; ++rr) {
                int rl = wm + i * 16 + kg * 4 + rr;
                int n  = bn + wn + j * 16 + lr;
                float v1 = acc1[i][j][rr], v2 = acc2[i][j][rr];
                h[(size_t)(hbase + rl) * 1024 + n] =
                    (bf16_t)(v1 / (1.f + __expf(-v1)) * v2);
            }
        }
    }
}

// ---------------------------------------------------------------------------
// Grouped routed down-proj, BK=64 dbuf (r5 form) + XCD-expert decode,
// weighted scatter-add into out.
// ---------------------------------------------------------------------------
__global__ __launch_bounds__(256) void down_gather(
    const bf16_t* __restrict__ h, const bf16_t* __restrict__ Wp,
    const int* __restrict__ tok_list, const float* __restrict__ w_list,
    const int* __restrict__ cnt, float* __restrict__ out)
{
    const int wg = blockIdx.y * 8 + blockIdx.x;   // dispatch-linear id
    const int e  = wg & 7;                        // XCD-aligned expert
    const int r_ = wg >> 3;
    const int t  = r_ & 31;
    const int bn = (r_ >> 5) * 128;
    const int ce = cnt[e];
    if (t * 128 >= ce) return;
    const int hbase = seg_off(cnt, e) + t * 128;
    const bf16_t* We = Wp + (size_t)e * 1048576;

    __shared__ __align__(16) bf16_t sA[2][128 * 64];
    __shared__ __align__(16) bf16_t sB[2][128 * 64];
    const int tid  = threadIdx.x;
    const int lane = tid & 63;
    const int wv   = tid >> 6;
    const int wm   = (wv >> 1) * 64, wn = (wv & 1) * 64;
    const int lr   = lane & 15;
    const int kg   = lane >> 4;
    const int swz  = (lr & 7) << 3;

    f32x4 acc[4][4];
    #pragma unroll
    for (int i = 0; i < 4; ++i)
        #pragma unroll
        for (int j = 0; j < 4; ++j)
            acc[i][j] = f32x4{0.f, 0.f, 0.f, 0.f};

    auto STAGE = [&](int b, int k0) {
        #pragma unroll
        for (int p = 0; p < 4; ++p) {
            int idx = p * 256 + tid;
            int row = idx >> 3;
            int ch  = ((idx & 7) * 8) ^ ((row & 7) << 3);
            GLD16(h  + (size_t)(hbase + row) * 1024 + k0 + ch, sA[b] + idx * 8);
            GLD16(We + (size_t)(bn + row) * 1024 + k0 + ch,    sB[b] + idx * 8);
        }
    };

    STAGE(0, 0);
    PIPE_BARRIER();
    int cur = 0;
    for (int k0 = 0; k0 < 1024; k0 += 64) {
        if (k0 + 64 < 1024) STAGE(cur ^ 1, k0 + 64);
        #pragma unroll
        for (int ks = 0; ks < 2; ++ks) {
            bf16x8 af[4], bfr[4];
            #pragma unroll
            for (int i = 0; i < 4; ++i)
                af[i] = *(const bf16x8*)(sA[cur] + (wm + i * 16 + lr) * 64 +
                                         ((ks * 32 + kg * 8) ^ swz));
            #pragma unroll
            for (int j = 0; j < 4; ++j)
                bfr[j] = *(const bf16x8*)(sB[cur] + (wn + j * 16 + lr) * 64 +
                                          ((ks * 32 + kg * 8) ^ swz));
            #pragma unroll
            for (int i = 0; i < 4; ++i)
                #pragma unroll
                for (int j = 0; j < 4; ++j)
                    acc[i][j] = __builtin_amdgcn_mfma_f32_16x16x32_bf16(
                        af[i], bfr[j], acc[i][j], 0, 0, 0);
        }
        PIPE_BARRIER();
        cur ^= 1;
    }

    #pragma unroll
    for (int i = 0; i < 4; ++i) {
        #pragma unroll
        for (int rr = 0; rr < 4; ++rr) {
            int g = t * 128 + wm + i * 16 + kg * 4 + rr;
            if (g < ce) {
                int   tok = tok_list[e * 4096 + g];
                float wgt = w_list[e * 4096 + g];
                #pragma unroll
                for (int j = 0; j < 4; ++j) {
                    int n = bn + wn + j * 16 + lr;
                    atomicAdd(&out[(size_t)tok * 1024 + n], wgt * acc[i][j][rr]);
                }
            }
        }
    }
}

// ---------------------------------------------------------------------------
// RMSNorm: fp32 src -> bf16 dst, row length 1024 (norm1)
// ---------------------------------------------------------------------------
__global__ __launch_bounds__(256) void rmsnorm_k(
    const float* __restrict__ src, const float* __restrict__ w,
    bf16_t* __restrict__ dst)
{
    const int row = blockIdx.x, tid = threadIdx.x;
    float4 t4 = *((const float4*)src + (size_t)row * 256 + tid);
    float ssum = t4.x*t4.x + t4.y*t4.y + t4.z*t4.z + t4.w*t4.w;
    #pragma unroll
    for (int off = 32; off > 0; off >>= 1) ssum += __shfl_down(ssum, off);
    __shared__ float red[4];
    if ((tid & 63) == 0) red[tid >> 6] = ssum;
    __syncthreads();
    float total = red[0] + red[1] + red[2] + red[3];
    float rms = rsqrtf(total * (1.0f / 1024.0f) + 1e-6f);
    float4 w4 = *((const float4*)w + tid);
    bf16x4 o4;
    o4[0] = (bf16_t)(t4.x * rms * w4.x);
    o4[1] = (bf16_t)(t4.y * rms * w4.y);
    o4[2] = (bf16_t)(t4.z * rms * w4.z);
    o4[3] = (bf16_t)(t4.w * rms * w4.w);
    *((bf16x4*)dst + (size_t)row * 256 + tid) = o4;
}

// ---------------------------------------------------------------------------
// Fused RMSNorm + MoE gate (fp32 logits in-register; no atomics).
// ---------------------------------------------------------------------------
__global__ __launch_bounds__(256) void rmsnorm_gate_k(
    const float* __restrict__ src, const float* __restrict__ w,
    const float* __restrict__ gw, bf16_t* __restrict__ dst,
    float* __restrict__ scores, int* __restrict__ topi,
    float* __restrict__ topw)
{
    const int row = blockIdx.x, tid = threadIdx.x;
    float4 t4 = *((const float4*)src + (size_t)row * 256 + tid);
    float ssum = t4.x*t4.x + t4.y*t4.y + t4.z*t4.z + t4.w*t4.w;
    #pragma unroll
    for (int off = 32; off > 0; off >>= 1) ssum += __shfl_down(ssum, off);
    __shared__ float red[4];
    if ((tid & 63) == 0) red[tid >> 6] = ssum;
    __syncthreads();
    float total = red[0] + red[1] + red[2] + red[3];
    float rms = rsqrtf(total * (1.0f / 1024.0f) + 1e-6f);
    float4 w4 = *((const float4*)w + tid);
    float4 f4;
    f4.x = t4.x * rms * w4.x;
    f4.y = t4.y * rms * w4.y;
    f4.z = t4.z * rms * w4.z;
    f4.w = t4.w * rms * w4.w;
    bf16x4 o4;
    o4[0] = (bf16_t)f4.x; o4[1] = (bf16_t)f4.y;
    o4[2] = (bf16_t)f4.z; o4[3] = (bf16_t)f4.w;
    *((bf16x4*)dst + (size_t)row * 256 + tid) = o4;

    float a[8];
    #pragma unroll
    for (int e = 0; e < 8; ++e) {
        float4 g4 = *((const float4*)(gw + (size_t)e * 1024) + tid);
        a[e] = f4.x * g4.x + f4.y * g4.y + f4.z * g4.z + f4.w * g4.w;
    }
    #pragma unroll
    for (int e = 0; e < 8; ++e)
        #pragma unroll
        for (int off = 32; off > 0; off >>= 1) a[e] += __shfl_down(a[e], off);
    __shared__ float gred[4][8];
    if ((tid & 63) == 0)
        #pragma unroll
        for (int e = 0; e < 8; ++e) gred[tid >> 6][e] = a[e];
    __syncthreads();
    if (tid == 0) {
        float lg[8];
        #pragma unroll
        for (int e = 0; e < 8; ++e)
            lg[e] = gred[0][e] + gred[1][e] + gred[2][e] + gred[3][e];
        #pragma unroll
        for (int e = 0; e < 8; ++e) scores[(size_t)row * 8 + e] = lg[e];
        float mx = lg[0];
        #pragma unroll
        for (int e = 1; e < 8; ++e) mx = fmaxf(mx, lg[e]);
        float p[8], sum = 0.f;
        #pragma unroll
        for (int e = 0; e < 8; ++e) { p[e] = __expf(lg[e] - mx); sum += p[e]; }
        float inv = 1.0f / sum;
        #pragma unroll
        for (int e = 0; e < 8; ++e) p[e] *= inv;
        int i1 = 0;
        #pragma unroll
        for (int e = 1; e < 8; ++e) if (p[e] > p[i1]) i1 = e;
        int i2 = (i1 == 0) ? 1 : 0;
        #pragma unroll
        for (int e = 0; e < 8; ++e) if (e != i1 && p[e] > p[i2]) i2 = e;
        topi[row] = i1 | (i2 << 8);
        topw[row * 2]     = p[i1];
        topw[row * 2 + 1] = p[i2];
    }
}

// ---------------------------------------------------------------------------
// Build per-expert token lists WITHOUT atomics (one block per expert).
// ---------------------------------------------------------------------------
__global__ __launch_bounds__(256) void build_lists_k(
    const int* __restrict__ topi, const float* __restrict__ topw,
    int* __restrict__ tok_list, float* __restrict__ w_list,
    int* __restrict__ cnt)
{
    const int e = blockIdx.x;
    const int tid = threadIdx.x, lane = tid & 63, wv = tid >> 6;
    __shared__ int wc[4];
    int base = 0;
    for (int t0 = 0; t0 < 4096; t0 += 256) {
        int tok = t0 + tid;
        int ti = topi[tok];
        int i1 = ti & 255, i2 = (ti >> 8) & 255;
        bool m = (i1 == e) || (i2 == e);
        unsigned long long b = __ballot(m);
        if (lane == 0) wc[wv] = __popcll(b);
        __syncthreads();
        int pos = base;
        #pragma unroll
        for (int k = 0; k < 4; ++k) if (k < wv) pos += wc[k];
        pos += __popcll(b & ((1ull << lane) - 1ull));
        if (m) {
            tok_list[e * 4096 + pos] = tok;
            w_list[e * 4096 + pos]   = (i1 == e) ? topw[tok * 2] : topw[tok * 2 + 1];
        }
        base += wc[0] + wc[1] + wc[2] + wc[3];
        __syncthreads();
    }
    int padded = (base + 127) & ~127;
    for (int p = base + tid; p < padded; p += 256) tok_list[e * 4096 + p] = 0;
    if (tid == 0) cnt[e] = base;
}

// ---------------------------------------------------------------------------
// RoPE in-place on qkv buffer (4096 x 1536)
// ---------------------------------------------------------------------------
__global__ __launch_bounds__(256) void rope_all_k(
    bf16_t* __restrict__ qkv, const float* __restrict__ fc)
{
    int idx = blockIdx.x * 256 + threadIdx.x;
    int pr = idx & 31;
    int hn = idx >> 5;
    int h  = hn % 20;
    int n  = hn / 20;
    int tpos = n & 1023;
    const float* f = fc + ((size_t)tpos * 32 + pr) * 2;
    float c = f[0], s = f[1];
    int col = (h < 16) ? h * 64 : 1024 + (h - 16) * 64;
    size_t base = (size_t)n * LQKV + col + pr * 2;
    float x0 = (float)qkv[base], x1 = (float)qkv[base + 1];
    qkv[base]     = (bf16_t)(x0 * c - x1 * s);
    qkv[base + 1] = (bf16_t)(x1 * c + x0 * s);
}

// ---------------------------------------------------------------------------
// V transpose: qkv V-part (cols 1280..1535) -> vt [(b*4+kvh)*64+d][1024]
// ---------------------------------------------------------------------------
__global__ __launch_bounds__(256) void transpose_v(
    const bf16_t* __restrict__ qkv, bf16_t* __restrict__ vt)
{
    __shared__ bf16_t tile[64][72];
    const int tt = blockIdx.x, kvh = blockIdx.y, b = blockIdx.z;
    const int tid = threadIdx.x;
    {
        int r = tid >> 2, c = (tid & 3) * 16;
        const bf16_t* src = qkv + ((size_t)(b * 1024 + tt * 64 + r)) * LQKV
                            + 1280 + kvh * 64 + c;
        bf16x8 v0 = *(const bf16x8*)src;
        bf16x8 v1 = *(const bf16x8*)(src + 8);
        *(bf16x8*)&tile[r][c] = v0;
        *(bf16x8*)&tile[r][c + 8] = v1;
    }
    __syncthreads();
    {
        int d = tid >> 2, t4 = (tid & 3) * 16;
        bf16_t* dst = vt + ((size_t)((b * 4 + kvh) * 64 + d)) * 1024 + tt * 64 + t4;
        bf16x8 o0, o1;
        #pragma unroll
        for (int u = 0; u < 8; ++u) {
            o0[u] = tile[t4 + u][d];
            o1[u] = tile[t4 + 8 + u][d];
        }
        *(bf16x8*)dst = o0;
        *(bf16x8*)(dst + 8) = o1;
    }
}

// ---------------------------------------------------------------------------
// MFMA flash attention, causal GQA. Grid (qt=16, h=16, b=4), 256 thr = 4 waves.
// ---------------------------------------------------------------------------
__global__ __launch_bounds__(256) void attn_mfma(
    const bf16_t* __restrict__ qkv, const bf16_t* __restrict__ vt,
    bf16_t* __restrict__ ob)
{
    const int qt = blockIdx.x, h = blockIdx.y, b = blockIdx.z;
    const int kvh = h >> 2;
    __shared__ __align__(16) bf16_t sK[64 * 64];
    __shared__ __align__(16) bf16_t sVt[64 * 64];
    __shared__ __align__(16) bf16_t sP[64 * 72];
    const int tid  = threadIdx.x;
    const int w    = tid >> 6;
    const int lane = tid & 63;
    const int lr   = lane & 15;
    const int kg   = lane >> 4;
    const int swz  = (lr & 7) << 3;

    bf16x8 qf[2];
    {
        const bf16_t* qrow = qkv + ((size_t)(b * 1024 + qt * 64 + w * 16 + lr)) * LQKV
                             + h * 64;
        qf[0] = *(const bf16x8*)(qrow + kg * 8);
        qf[1] = *(const bf16x8*)(qrow + 32 + kg * 8);
    }
    float m_run[4], l_run[4];
    f32x4 o_acc[4];
    #pragma unroll
    for (int rr = 0; rr < 4; ++rr) { m_run[rr] = -1.0e30f; l_run[rr] = 0.f; }
    #pragma unroll
    for (int dt = 0; dt < 4; ++dt) o_acc[dt] = f32x4{0.f, 0.f, 0.f, 0.f};

    for (int kt = 0; kt <= qt; ++kt) {
        #pragma unroll
        for (int p = 0; p < 2; ++p) {
            int idx = p * 256 + tid;
            int row = idx >> 3;
            int chs = ((idx & 7) * 8) ^ ((row & 7) << 3);
            GLD16(qkv + ((size_t)(b * 1024 + kt * 64 + row)) * LQKV
                      + 1024 + kvh * 64 + chs, sK + idx * 8);
            GLD16(vt + ((size_t)((b * 4 + kvh) * 64 + row)) * 1024 + kt * 64 + chs,
                  sVt + idx * 8);
        }
        __syncthreads();

        f32x4 sfr[4];
        #pragma unroll
        for (int j = 0; j < 4; ++j) {
            sfr[j] = f32x4{0.f, 0.f, 0.f, 0.f};
            #pragma unroll
            for (int ks = 0; ks < 2; ++ks) {
                bf16x8 bf = *(const bf16x8*)(sK + (j * 16 + lr) * 64 +
                                             ((ks * 32 + kg * 8) ^ swz));
                sfr[j] = __builtin_amdgcn_mfma_f32_16x16x32_bf16(qf[ks], bf, sfr[j], 0, 0, 0);
            }
        }
        const int rowg = qt * 64 + w * 16 + kg * 4;
        float mnew[4];
        #pragma unroll
        for (int rr = 0; rr < 4; ++rr) mnew[rr] = m_run[rr];
        #pragma unroll
        for (int j = 0; j < 4; ++j) {
            int colg = kt * 64 + j * 16 + lr;
            #pragma unroll
            for (int rr = 0; rr < 4; ++rr) {
                float s = sfr[j][rr] * 0.125f;
                if (colg > rowg + rr) s = -1.0e30f;
                sfr[j][rr] = s;
                mnew[rr] = fmaxf(mnew[rr], s);
            }
        }
        #pragma unroll
        for (int off = 1; off < 16; off <<= 1)
            #pragma unroll
            for (int rr = 0; rr < 4; ++rr)
                mnew[rr] = fmaxf(mnew[rr], __shfl_xor(mnew[rr], off, 64));
        float alpha[4], lpart[4];
        #pragma unroll
        for (int rr = 0; rr < 4; ++rr) {
            alpha[rr] = __expf(m_run[rr] - mnew[rr]);
            lpart[rr] = 0.f;
        }
        #pragma unroll
        for (int j = 0; j < 4; ++j)
            #pragma unroll
            for (int rr = 0; rr < 4; ++rr) {
                float p = __expf(sfr[j][rr] - mnew[rr]);
                sfr[j][rr] = p;
                lpart[rr] += p;
            }
        #pragma unroll
        for (int j = 0; j < 4; ++j)
            #pragma unroll
            for (int rr = 0; rr < 4; ++rr)
                sP[(w * 16 + kg * 4 + rr) * 72 + j * 16 + lr] = (bf16_t)sfr[j][rr];
        #pragma unroll
        for (int off = 1; off < 16; off <<= 1)
            #pragma unroll
            for (int rr = 0; rr < 4; ++rr)
                lpart[rr] += __shfl_xor(lpart[rr], off, 64);
        #pragma unroll
        for (int rr = 0; rr < 4; ++rr) {
            l_run[rr] = l_run[rr] * alpha[rr] + lpart[rr];
            m_run[rr] = mnew[rr];
        }
        #pragma unroll
        for (int dt = 0; dt < 4; ++dt)
            #pragma unroll
            for (int rr = 0; rr < 4; ++rr)
                o_acc[dt][rr] *= alpha[rr];
        #pragma unroll
        for (int ks = 0; ks < 2; ++ks) {
            bf16x8 af = *(const bf16x8*)(sP + (w * 16 + lr) * 72 + ks * 32 + kg * 8);
            #pragma unroll
            for (int dt = 0; dt < 4; ++dt) {
                bf16x8 bf = *(const bf16x8*)(sVt + (dt * 16 + lr) * 64 +
                                             ((ks * 32 + kg * 8) ^ swz));
                o_acc[dt] = __builtin_amdgcn_mfma_f32_16x16x32_bf16(af, bf, o_acc[dt], 0, 0, 0);
            }
        }
        __syncthreads();
    }

    float inv[4];
    #pragma unroll
    for (int rr = 0; rr < 4; ++rr) inv[rr] = 1.0f / l_run[rr];
    #pragma unroll
    for (int dt = 0; dt < 4; ++dt)
        #pragma unroll
        for (int rr = 0; rr < 4; ++rr) {
            int tok = qt * 64 + w * 16 + kg * 4 + rr;
            ob[((size_t)(b * 1024 + tok)) * 1024 + h * 64 + dt * 16 + lr] =
                (bf16_t)(o_acc[dt][rr] * inv[rr]);
        }
}

// ---------------------------------------------------------------------------
extern "C" void kernel_launch(void* const* d_in, const int* in_sizes, int n_in,
                              void* d_out, int out_size, void* d_ws, size_t ws_size,
                              hipStream_t stream)
{
    const float* x   = (const float*)d_in[0];
    const float* fc  = (const float*)d_in[1];
    const float* n1w = (const float*)d_in[4];
    const float* wq  = (const float*)d_in[5];
    const float* wk  = (const float*)d_in[6];
    const float* wv  = (const float*)d_in[7];
    const float* wo  = (const float*)d_in[8];
    const float* n2w = (const float*)d_in[9];
    const float* gw  = (const float*)d_in[10];
    const float* ew1 = (const float*)d_in[11];
    const float* ew2 = (const float*)d_in[12];
    const float* ewp = (const float*)d_in[13];
    const float* sw1 = (const float*)d_in[14];
    const float* sw2 = (const float*)d_in[15];
    const float* swp = (const float*)d_in[16];

    // ---- workspace (peak ~93 MB; phase-aliased) ----
    const size_t MB = 1024 * 1024;
    char* ws = (char*)d_ws;
    bf16_t* xnb  = (bf16_t*)(ws + 0);         // [0,8)   xn / xn2 bf16
    float*  x1   = (float*) (ws + 8 * MB);    // [8,24)  residual fp32 (dead after gate)
    bf16_t* ew2b = (bf16_t*)(ws + 8 * MB);    //         ... then expert W2 bf16
    bf16_t* h    = (bf16_t*)(ws + 24 * MB);   // [24,42) routed GLU out (9216x1024)
    char*   lists= ws + 42 * MB;              // [42,43) routing lists
    int*    tok_list = (int*)lists;
    float*  w_list   = (float*)(lists + 131072);
    int*    cnt      = (int*)(lists + 262144);
    int*    topi     = (int*)(lists + 262400);
    float*  topw     = (float*)(lists + 278784);
    bf16_t* sw1b = (bf16_t*)(ws + 43 * MB);   // [43,47) shared W1 bf16
    bf16_t* sw2b = (bf16_t*)(ws + 47 * MB);   // [47,51) shared W2 bf16
    bf16_t* swpb = (bf16_t*)(ws + 51 * MB);   // [51,55) shared Wp bf16
    char*   slotA= ws + 55 * MB;              // [55,71) attn weights -> shared hb
    bf16_t* hb   = (bf16_t*)slotA;            //         shared GLU out (4096x2048)
    bf16_t* qkv  = (bf16_t*)(ws + 71 * MB);   // [71,83) fused QKV (4096x1536)
    bf16_t* ob   = (bf16_t*)(ws + 83 * MB);   // [83,91) attn out
    bf16_t* vt   = (bf16_t*)(ws + 91 * MB);   // [91,93) V transposed
    bf16_t* ew1b = (bf16_t*)(ws + 71 * MB);   // [71,87) expert W1 (qkv/ob dead)
    bf16_t* ewpb = (bf16_t*)(ws + 71 * MB);   // [71,87) expert Wp (after GLU)

    float* outp   = (float*)d_out;
    float* scores = outp + (size_t)4096 * 1024;

    auto gemm = [&](const bf16_t* A, const bf16_t* W, int M, int N, int K, int ldw,
                    int mode, float* oF, bf16_t* oB, const float* res, float* oF2) {
        gemm_bt<<<dim3(N / 128, M / 128), 256, 0, stream>>>(
            A, W, M, N, K, ldw, mode, oF, oB, res, oF2);
    };

    // ---- batched weight conversion #1: attn (QKV contiguous) + shared ----
    bf16_t* wqb = (bf16_t*)slotA;             // [wqb..] 1536x1024 contiguous
    bf16_t* wkb = wqb + 1048576;
    bf16_t* wvb = wkb + 262144;
    bf16_t* wob = wvb + 262144;
    {
        Cvt8 j;
        j.s[0]=wq;  j.d[0]=wqb;  j.s[1]=wk;  j.d[1]=wkb;
        j.s[2]=wv;  j.d[2]=wvb;  j.s[3]=wo;  j.d[3]=wob;
        j.s[4]=sw1; j.d[4]=sw1b; j.s[5]=sw2; j.d[5]=sw2b;
        j.s[6]=swp; j.d[6]=swpb; j.s[7]=nullptr; j.d[7]=nullptr;
        int sz[7] = {1024, 256, 256, 1024, 2048, 2048, 2048};
        j.cum[0] = 0;
        for (int k = 0; k < 7; ++k) j.cum[k + 1] = j.cum[k] + sz[k];
        j.cum[8] = j.cum[7];
        j.nseg = 7;
        convert_multi_k<<<j.cum[7], 256, 0, stream>>>(j);
    }

    // ---- attention ----
    rmsnorm_k<<<4096, 256, 0, stream>>>(x, n1w, xnb);
    gemm(xnb, wqb, 4096, LQKV, 1024, 1024, 1, nullptr, qkv, nullptr, nullptr);
    rope_all_k<<<(4096 * 20 * 32) / 256, 256, 0, stream>>>(qkv, fc);
    transpose_v<<<dim3(16, 4, 4), 256, 0, stream>>>(qkv, vt);
    attn_mfma<<<dim3(16, 16, 4), 256, 0, stream>>>(qkv, vt, ob);
    gemm(ob, wob, 4096, 1024, 1024, 1024, 2, x1, nullptr, x, outp);

    // ---- MoE: fused norm2+gate, atomics-free list build ----
    rmsnorm_gate_k<<<4096, 256, 0, stream>>>(x1, n2w, gw, xnb, scores, topi, topw);
    build_lists_k<<<8, 256, 0, stream>>>(topi, topw, tok_list, w_list, cnt);

    // ---- batched weight conversion #2: expert W1 + W2 ----
    {
        Cvt8 j;
        j.s[0]=ew1; j.d[0]=ew1b; j.s[1]=ew2; j.d[1]=ew2b;
        for (int k = 2; k < 8; ++k) { j.s[k]=nullptr; j.d[k]=nullptr; }
        j.cum[0] = 0; j.cum[1] = 8192; j.cum[2] = 16384;
        for (int k = 3; k < 9; ++k) j.cum[k] = 16384;
        j.nseg = 2;
        convert_multi_k<<<16384, 256, 0, stream>>>(j);
    }

    // ---- GLU: shared (dense) then routed (grouped gather, XCD-aligned) ----
    gemm_glu<<<dim3(16, 32), 256, 0, stream>>>(xnb, sw1b, sw2b, 4096, 2048, 1024, hb);
    glu_gather<<<dim3(8, 256), 256, 0, stream>>>(xnb, ew1b, ew2b, tok_list, cnt, h);

    // ---- expert Wp conversion (ew1b dead after GLU) ----
    convert_k<<<8192, 256, 0, stream>>>(ewp, ewpb);

    // ---- down-proj: shared (outp += hb@swp^T, non-atomic), then routed ----
    gemm(hb, swpb, 4096, 1024, 2048, 2048, 3, outp, nullptr, nullptr, nullptr);
    down_gather<<<dim3(8, 256), 256, 0, stream>>>(h, ewpb, tok_list, w_list, cnt, outp);

    (void)in_sizes; (void)n_in; (void)out_size; (void)ws_size;
}